// Round 15
// baseline (279.985 us; speedup 1.0000x reference)
//
#include <hip/hip_runtime.h>

#define Bc 2
#define Sc 2048
#define Dc 2048
#define Hc 16
#define HDc 128
#define Mc 4096

typedef __bf16 bf16_t;
typedef __bf16 bf16x4 __attribute__((ext_vector_type(4)));
typedef __bf16 bf16x8 __attribute__((ext_vector_type(8)));
typedef float f32x4 __attribute__((ext_vector_type(4)));
typedef float f32x16 __attribute__((ext_vector_type(16)));

__device__ __forceinline__ f32x4 mfma16(bf16x8 a, bf16x8 b, f32x4 c) {
  return __builtin_amdgcn_mfma_f32_16x16x32_bf16(a, b, c, 0, 0, 0);
}
__device__ __forceinline__ f32x16 mfma32(bf16x8 a, bf16x8 b, f32x16 c) {
  return __builtin_amdgcn_mfma_f32_32x32x16_bf16(a, b, c, 0, 0, 0);
}

typedef const unsigned __attribute__((address_space(1))) gu32_t;
typedef unsigned __attribute__((address_space(3))) lu32_t;

__device__ __forceinline__ void gload_lds16(const void* g, void* l) {
  gu32_t* gp = (gu32_t*)(unsigned long long)g;
  lu32_t* lp = (lu32_t*)(unsigned)(unsigned long long)l;
  __builtin_amdgcn_global_load_lds(gp, lp, 16, 0, 0);
}

__device__ __forceinline__ unsigned cvtpk(float lo, float hi_) {
  unsigned r;
  asm("v_cvt_pk_bf16_f32 %0, %1, %2" : "=v"(r) : "v"(lo), "v"(hi_));
  return r;
}
__device__ __forceinline__ void plswap(unsigned& a, unsigned& b) {
  asm volatile("v_permlane32_swap_b32 %0, %1" : "+v"(a), "+v"(b));
}
// hardware 2^x (v_exp_f32 computes exp2 directly on gfx9xx)
__device__ __forceinline__ float fexp2(float x) {
  float r;
  asm("v_exp_f32 %0, %1" : "=v"(r) : "v"(x));
  return r;
}

// ---------------- convert x: fp32 -> bf16 ----------------
__global__ void cvt_bf16_kernel(const float* __restrict__ in, bf16_t* __restrict__ out, int n4) {
  int i = blockIdx.x * blockDim.x + threadIdx.x;
  if (i < n4) {
    float4 v = ((const float4*)in)[i];
    bf16x4 o;
    o[0] = (bf16_t)v.x; o[1] = (bf16_t)v.y; o[2] = (bf16_t)v.z; o[3] = (bf16_t)v.w;
    ((bf16x4*)out)[i] = o;
  }
}

// ---------------- rope cos/sin table: [2048][64] float2 ----------------
__global__ void rope_table_kernel(float2* __restrict__ tbl) {
  const int s = blockIdx.x, j = threadIdx.x;
  float freq = expf(-(float)j * (9.210340371976184f / 64.0f));
  float ang = (float)s * freq;
  float sn, cs;
  sincosf(ang, &sn, &cs);
  tbl[s * 64 + j] = make_float2(cs, sn);
}

// ---------------- transpose-convert 4 weights: (K,N) fp32 -> (N,K) bf16 ----------------
__global__ void transpose_cvt4_kernel(const float* __restrict__ w0, const float* __restrict__ w1,
                                      const float* __restrict__ w2, const float* __restrict__ w3,
                                      bf16_t* __restrict__ dqkv, bf16_t* __restrict__ dwo) {
  __shared__ float tile[32][33];
  const int z = blockIdx.z;
  const float* w = z == 0 ? w0 : (z == 1 ? w1 : (z == 2 ? w2 : w3));
  bf16_t* wt = z < 3 ? dqkv + (size_t)z * Dc * Dc : dwo;
  const int tx = threadIdx.x, ty = threadIdx.y;
  const int n0 = blockIdx.x * 32, k0 = blockIdx.y * 32;
#pragma unroll
  for (int i = 0; i < 32; i += 8)
    tile[ty + i][tx] = w[(size_t)(k0 + ty + i) * Dc + n0 + tx];
  __syncthreads();
#pragma unroll
  for (int i = 0; i < 32; i += 8)
    wt[(size_t)(n0 + ty + i) * Dc + k0 + tx] = (bf16_t)tile[tx][ty + i];
}

// ---------------- QKV GEMM: 256x256, BK=64, dbuf-2, per-wave 128x64 ----------------
// 8 waves = 2M x 4N. LDS 128 KiB. Full-iteration-lead staging (stage t+1 after
// barrier t; vmcnt(0) at top has ~1 iter of slack). Fused interleaved RoPE.
template <int NT>
__global__ __launch_bounds__(512, 1) void gemmq_kernel(
    const bf16_t* __restrict__ A, const bf16_t* __restrict__ Bt,
    const float* __restrict__ bias0, const float* __restrict__ bias1,
    const float* __restrict__ bias2, const float2* __restrict__ tbl,
    void* __restrict__ out0, void* __restrict__ out1, void* __restrict__ out2) {
  __shared__ __align__(16) bf16_t sA[2][256 * 64];  // 64 KB
  __shared__ __align__(16) bf16_t sB[2][256 * 64];  // 64 KB
  const int tid = threadIdx.x;
  const int lane = tid & 63, wid = tid >> 6;
  const int l15 = lane & 15, g = lane >> 4;
  const int wr = wid >> 2, wc = wid & 3;  // 2M x 4N waves; per-wave 128x64

  const int nwg = 16 * NT, cpx = nwg / 8;
  const int wgid = ((int)blockIdx.x & 7) * cpx + ((int)blockIdx.x >> 3);
  const int nt = wgid % NT, mt = wgid / NT;
  const int m0 = mt * 256, n0 = nt * 256;

  const bf16_t* Ab = A + (size_t)m0 * 2048;
  const bf16_t* Bb = Bt + (size_t)n0 * 2048;

  // stage K-tile kt (64 wide, 256 rows each of A and B): 8 loads/thread
#define GQ_STAGE(kt)                                                  \
  {                                                                   \
    const int sl_ = (kt) & 1;                                         \
    _Pragma("unroll") for (int i_ = 0; i_ < 4; ++i_) {                \
      int s_ = i_ * 512 + tid;                                        \
      int r_ = s_ >> 3;                                               \
      int c_ = ((s_ & 7) ^ (r_ & 7)) * 8;                             \
      gload_lds16(Ab + (size_t)r_ * 2048 + (kt) * 64 + c_,            \
                  (char*)&sA[sl_][0] + s_ * 16);                      \
    }                                                                 \
    _Pragma("unroll") for (int i_ = 0; i_ < 4; ++i_) {                \
      int s_ = i_ * 512 + tid;                                        \
      int r_ = s_ >> 3;                                               \
      int c_ = ((s_ & 7) ^ (r_ & 7)) * 8;                             \
      gload_lds16(Bb + (size_t)r_ * 2048 + (kt) * 64 + c_,            \
                  (char*)&sB[sl_][0] + s_ * 16);                      \
    }                                                                 \
  }

  f32x4 acc[8][4] = {};

  GQ_STAGE(0);

  for (int t = 0; t < 32; ++t) {
    asm volatile("s_waitcnt vmcnt(0)" ::: "memory");  // tile t fully landed
    __builtin_amdgcn_s_barrier();  // all waves done reading tile t-1
    __builtin_amdgcn_sched_barrier(0);
    if (t < 31) GQ_STAGE(t + 1);  // into other slot; safe by the barrier above
    const char* pA = (const char*)&sA[t & 1][0];
    const char* pB = (const char*)&sB[t & 1][0];
#pragma unroll
    for (int ks = 0; ks < 2; ++ks) {
      bf16x8 af[8], bfr[4];
#pragma unroll
      for (int mi = 0; mi < 8; ++mi) {
        int r = wr * 128 + mi * 16 + l15;
        af[mi] = *(const bf16x8*)(pA + r * 128 + (((ks * 4 + g) ^ (r & 7)) * 16));
      }
#pragma unroll
      for (int ni = 0; ni < 4; ++ni) {
        int r = wc * 64 + ni * 16 + l15;
        bfr[ni] = *(const bf16x8*)(pB + r * 128 + (((ks * 4 + g) ^ (r & 7)) * 16));
      }
      __builtin_amdgcn_s_setprio(1);
#pragma unroll
      for (int mi = 0; mi < 8; ++mi)
#pragma unroll
        for (int ni = 0; ni < 4; ++ni)
          acc[mi][ni] = mfma16(af[mi], bfr[ni], acc[mi][ni]);
      __builtin_amdgcn_s_setprio(0);
    }
  }

#undef GQ_STAGE

  // epilogue: fused interleaved RoPE on Q,K; V transposed store
  const int proj = n0 >> 11;  // block-uniform (256 | 2048)
  const float* bp = proj == 0 ? bias0 : (proj == 1 ? bias1 : bias2);
  bf16_t* op = (bf16_t*)(proj == 0 ? out0 : (proj == 1 ? out1 : out2));
#pragma unroll
  for (int mi = 0; mi < 8; ++mi) {
#pragma unroll
    for (int ni = 0; ni < 4; ++ni) {
      const int ncol = n0 + wc * 64 + ni * 16 + l15;
      const int nloc = ncol & 2047;
      const float bv = bp[nloc];
      const int h = nloc >> 7, hd = nloc & 127;
      if (proj < 2) {
        const int j = hd >> 1;
#pragma unroll
        for (int r = 0; r < 4; ++r) {
          const int mrow = m0 + wr * 128 + mi * 16 + g * 4 + r;
          const int b = mrow >> 11, sq = mrow & 2047;
          float vv = acc[mi][ni][r] + bv;
          float part = __shfl_xor(vv, 1);
          float2 cn = tbl[(size_t)sq * 64 + j];
          float ov = (l15 & 1) ? (part * cn.y + vv * cn.x)
                               : (vv * cn.x - part * cn.y);
          op[(((size_t)(b * Hc + h) * Sc + sq) * HDc) + hd] = (bf16_t)ov;
        }
      } else {
#pragma unroll
        for (int r = 0; r < 4; ++r) {
          const int mrow = m0 + wr * 128 + mi * 16 + g * 4 + r;
          const int b = mrow >> 11, sq = mrow & 2047;
          const float v = acc[mi][ni][r] + bv;
          op[(((size_t)(b * Hc + h) * HDc + hd) * Sc) + sq] = (bf16_t)v;
        }
      }
    }
  }
}

// ---------------- out-proj GEMM: 256x128, BK=64, ring-3, 2-phase (r6 proven) ----------------
template <int NT8>
__global__ __launch_bounds__(512, 1) void gemmp_kernel(
    const bf16_t* __restrict__ A, const bf16_t* __restrict__ Bt,
    const float* __restrict__ bias0, void* __restrict__ out0) {
  __shared__ __align__(16) bf16_t sA[3][256 * 64];  // 96 KB
  __shared__ __align__(16) bf16_t sB[3][128 * 64];  // 48 KB
  const int tid = threadIdx.x;
  const int lane = tid & 63, wid = tid >> 6;
  const int l15 = lane & 15, g = lane >> 4;
  const int wrow = wid >> 1, wcol = wid & 1;

  const int nwg = 16 * NT8, cpx = nwg / 8;
  const int wgid = ((int)blockIdx.x & 7) * cpx + ((int)blockIdx.x >> 3);
  const int nt = wgid % NT8, mt = wgid / NT8;
  const int m0 = mt * 256, n0 = nt * 128;

  const bf16_t* Ab = A + (size_t)m0 * 2048;
  const bf16_t* Bb = Bt + (size_t)n0 * 2048;

#define GP_STAGE_A(kt, i_)                                           \
  {                                                                  \
    int s_ = (i_) * 512 + tid;                                       \
    int r_ = s_ >> 3;                                                \
    int c_ = ((s_ & 7) ^ (r_ & 7)) * 8;                              \
    gload_lds16(Ab + (size_t)r_ * 2048 + (kt) * 64 + c_,             \
                (char*)&sA[(kt) % 3][0] + s_ * 16);                  \
  }
#define GP_STAGE_B(kt, i_)                                           \
  {                                                                  \
    int s_ = (i_) * 512 + tid;                                       \
    int r_ = s_ >> 3;                                                \
    int c_ = ((s_ & 7) ^ (r_ & 7)) * 8;                              \
    gload_lds16(Bb + (size_t)r_ * 2048 + (kt) * 64 + c_,             \
                (char*)&sB[(kt) % 3][0] + s_ * 16);                  \
  }

  f32x4 acc[4][4] = {};

  GP_STAGE_A(0, 0) GP_STAGE_A(0, 1) GP_STAGE_A(0, 2) GP_STAGE_A(0, 3)
  GP_STAGE_B(0, 0) GP_STAGE_B(0, 1)
  GP_STAGE_A(1, 0) GP_STAGE_A(1, 1) GP_STAGE_A(1, 2) GP_STAGE_A(1, 3)
  GP_STAGE_B(1, 0) GP_STAGE_B(1, 1)

#define GP_BODY(t, DOSTG, VMSTR)                                               \
  {                                                                            \
    asm volatile("s_waitcnt vmcnt(" VMSTR ")" ::: "memory");                   \
    __builtin_amdgcn_s_barrier();                                              \
    __builtin_amdgcn_sched_barrier(0);                                         \
    const char* pA = (const char*)&sA[(t) % 3][0];                             \
    const char* pB = (const char*)&sB[(t) % 3][0];                             \
    bf16x8 af[4][2], bf0[2][2], bf1[2][2];                                     \
    _Pragma("unroll") for (int mi = 0; mi < 4; ++mi)                           \
        _Pragma("unroll") for (int ks = 0; ks < 2; ++ks) {                     \
      int r = wrow * 64 + mi * 16 + l15;                                       \
      af[mi][ks] = *(const bf16x8*)(pA + r * 128 + (((ks * 4 + g) ^ (r & 7)) * 16)); \
    }                                                                          \
    _Pragma("unroll") for (int ni = 0; ni < 2; ++ni)                           \
        _Pragma("unroll") for (int ks = 0; ks < 2; ++ks) {                     \
      int r = wcol * 64 + ni * 16 + l15;                                       \
      bf0[ni][ks] = *(const bf16x8*)(pB + r * 128 + (((ks * 4 + g) ^ (r & 7)) * 16)); \
    }                                                                          \
    if (DOSTG) { GP_STAGE_A((t) + 2, 0) GP_STAGE_A((t) + 2, 1) GP_STAGE_B((t) + 2, 0) } \
    __builtin_amdgcn_s_setprio(1);                                             \
    _Pragma("unroll") for (int mi = 0; mi < 4; ++mi)                           \
        _Pragma("unroll") for (int ni = 0; ni < 2; ++ni)                       \
            _Pragma("unroll") for (int ks = 0; ks < 2; ++ks)                   \
                acc[mi][ni] = mfma16(af[mi][ks], bf0[ni][ks], acc[mi][ni]);    \
    __builtin_amdgcn_s_setprio(0);                                             \
    __builtin_amdgcn_s_barrier();                                              \
    __builtin_amdgcn_sched_barrier(0);                                         \
    _Pragma("unroll") for (int ni = 0; ni < 2; ++ni)                           \
        _Pragma("unroll") for (int ks = 0; ks < 2; ++ks) {                     \
      int r = wcol * 64 + (ni + 2) * 16 + l15;                                 \
      bf1[ni][ks] = *(const bf16x8*)(pB + r * 128 + (((ks * 4 + g) ^ (r & 7)) * 16)); \
    }                                                                          \
    if (DOSTG) { GP_STAGE_A((t) + 2, 2) GP_STAGE_A((t) + 2, 3) GP_STAGE_B((t) + 2, 1) } \
    __builtin_amdgcn_s_setprio(1);                                             \
    _Pragma("unroll") for (int mi = 0; mi < 4; ++mi)                           \
        _Pragma("unroll") for (int ni = 0; ni < 2; ++ni)                       \
            _Pragma("unroll") for (int ks = 0; ks < 2; ++ks)                   \
                acc[mi][ni + 2] = mfma16(af[mi][ks], bf1[ni][ks], acc[mi][ni + 2]); \
    __builtin_amdgcn_s_setprio(0);                                             \
  }

  for (int t = 0; t < 30; ++t) GP_BODY(t, 1, "6");
  GP_BODY(30, 0, "6");
  GP_BODY(31, 0, "0");

#undef GP_BODY
#undef GP_STAGE_A
#undef GP_STAGE_B

#pragma unroll
  for (int mi = 0; mi < 4; ++mi) {
#pragma unroll
    for (int ni = 0; ni < 4; ++ni) {
      const int ncol = n0 + wcol * 64 + ni * 16 + l15;
      const float bv = bias0[ncol];
#pragma unroll
      for (int r = 0; r < 4; ++r) {
        const int mrow = m0 + wrow * 64 + mi * 16 + g * 4 + r;
        ((float*)out0)[(size_t)mrow * 2048 + ncol] = acc[mi][ni][r] + bv;
      }
    }
  }
}

// ---------------- flash attention, 32x32 swapped-QK^T, LDS dbuf K/V ----------------
__global__ __launch_bounds__(256, 2) void attn_kernel(
    const bf16_t* __restrict__ Q, const bf16_t* __restrict__ Kr,
    const bf16_t* __restrict__ Vt, const int* __restrict__ mask,
    bf16_t* __restrict__ AO) {
  __shared__ __align__(16) bf16_t sK[2][64 * 128];
  __shared__ __align__(16) bf16_t sV[2][64 * 128];
  __shared__ float mbias[Sc];
  __shared__ float bcast[4][32];
  const int tid = threadIdx.x;
  const int w = tid >> 6, lane = tid & 63;
  const int l31 = lane & 31, hi = lane >> 5;
  const int wbase = w * 64;

  const int bid = blockIdx.x;
  const int L = ((bid & 7) << 6) + (bid >> 3);
  const int qc = L & 15, h = (L >> 4) & 15, b = L >> 8;

  const int* mb = mask + b * Sc;
#pragma unroll
  for (int i = 0; i < Sc / 256; ++i)
    mbias[i * 256 + tid] = mb[i * 256 + tid] ? 0.f : -1.4426950408889634e9f;

  const int q0 = qc * 128 + w * 32;
  const bf16_t* qb = Q + ((size_t)(b * Hc + h) * Sc + q0) * HDc;
  const bf16_t* kb = Kr + ((size_t)(b * Hc + h) * Sc) * HDc;
  const bf16_t* vb = Vt + ((size_t)(b * Hc + h) * HDc) * Sc;

  bf16x8 qf[8];
  {
    const bf16_t* qr = qb + (size_t)l31 * HDc + hi * 8;
#pragma unroll
    for (int kk = 0; kk < 8; ++kk) qf[kk] = *(const bf16x8*)(qr + kk * 16);
  }

#define STAGE_KV(sKb, sVb, kv0_)                                             \
  {                                                                          \
    _Pragma("unroll") for (int p = 0; p < 4; ++p) {                          \
      int s_ = p * 256 + tid;                                                \
      int rk = s_ >> 4, ck = s_ & 15;                                        \
      gload_lds16(kb + (size_t)((kv0_) + rk) * HDc + ((ck ^ (rk & 15)) * 8), \
                  (char*)(sKb) + (size_t)(p * 256 + wbase) * 16);            \
      int d63 = s_ >> 4, sv = s_ & 15;                                       \
      int tmp = sv ^ (d63 & 15);                                             \
      int hb = tmp >> 3, cv = tmp & 7;                                       \
      gload_lds16(vb + (size_t)(hb * 64 + d63) * Sc + (kv0_) + cv * 8,       \
                  (char*)(sVb) + (size_t)(p * 256 + wbase) * 16);            \
    }                                                                        \
  }

  bf16_t* sKc = &sK[0][0];
  bf16_t* sKn = &sK[1][0];
  bf16_t* sVc = &sV[0][0];
  bf16_t* sVn = &sV[1][0];

  STAGE_KV(sKc, sVc, 0);
  asm volatile("s_waitcnt vmcnt(0)" ::: "memory");
  __syncthreads();

  f32x16 acc[4];
#pragma unroll
  for (int d = 0; d < 4; ++d) acc[d] = 0.f;
  float mrun = -3.0e38f, lrun = 0.f;
  const float scale2 = 0.12751744f;  // 128^-0.5 * log2(e)

  for (int kv0 = 0; kv0 < Sc; kv0 += 64) {
    if (kv0 + 64 < Sc) STAGE_KV(sKn, sVn, kv0 + 64);

    f32x16 s0 = 0.f, s1 = 0.f;
    {
      const char* kbase = (const char*)sKc;
      __builtin_amdgcn_s_setprio(1);
#pragma unroll
      for (int kk = 0; kk < 8; ++kk) {
        bf16x8 k0f = *(const bf16x8*)(kbase + l31 * 256 + (((2 * kk + hi) ^ (l31 & 15)) * 16));
        bf16x8 k1f = *(const bf16x8*)(kbase + (32 + l31) * 256 + (((2 * kk + hi) ^ ((32 + l31) & 15)) * 16));
        s0 = mfma32(k0f, qf[kk], s0);
        s1 = mfma32(k1f, qf[kk], s1);
      }
      __builtin_amdgcn_s_setprio(0);
    }
    float v[32];
    {
      const float* mp = mbias + kv0 + 4 * hi;
#pragma unroll
      for (int g4 = 0; g4 < 4; ++g4) {
        f32x4 b0 = *(const f32x4*)(mp + 8 * g4);
        f32x4 b1 = *(const f32x4*)(mp + 32 + 8 * g4);
#pragma unroll
        for (int j = 0; j < 4; ++j) {
          v[g4 * 4 + j] = s0[g4 * 4 + j] * scale2 + b0[j];
          v[16 + g4 * 4 + j] = s1[g4 * 4 + j] * scale2 + b1[j];
        }
      }
    }
    float t16[16];
#pragma unroll
    for (int r = 0; r < 16; ++r) t16[r] = fmaxf(v[r], v[r + 16]);
#pragma unroll
    for (int r = 0; r < 8; ++r) t16[r] = fmaxf(t16[r], t16[r + 8]);
#pragma unroll
    for (int r = 0; r < 4; ++r) t16[r] = fmaxf(t16[r], t16[r + 4]);
    float tm = fmaxf(fmaxf(t16[0], t16[1]), fmaxf(t16[2], t16[3]));
    tm = fmaxf(tm, __shfl_xor(tm, 32));
    if (__any(tm > mrun + 11.5415603f)) {
      float mnew = fmaxf(mrun, tm);
      float al = fexp2(mrun - mnew);
      mrun = mnew;
      lrun *= al;
      bcast[w][l31] = al;
      asm volatile("s_waitcnt lgkmcnt(0)" ::: "memory");
      __builtin_amdgcn_sched_barrier(0);
#pragma unroll
      for (int g4 = 0; g4 < 4; ++g4) {
        f32x4 alr = *(const f32x4*)(&bcast[w][8 * g4 + 4 * hi]);
#pragma unroll
        for (int dblk = 0; dblk < 4; ++dblk)
#pragma unroll
          for (int j = 0; j < 4; ++j) acc[dblk][g4 * 4 + j] *= alr[j];
      }
    }
    float ts = 0.f;
#pragma unroll
    for (int r = 0; r < 32; ++r) {
      v[r] = fexp2(v[r] - mrun);
      ts += v[r];
    }
    ts += __shfl_xor(ts, 32);
    lrun += ts;
    unsigned pk[4][4];
#pragma unroll
    for (int ks = 0; ks < 4; ++ks) {
      unsigned a1 = cvtpk(v[ks * 8 + 0], v[ks * 8 + 1]);
      unsigned b1 = cvtpk(v[ks * 8 + 4], v[ks * 8 + 5]);
      unsigned a2 = cvtpk(v[ks * 8 + 2], v[ks * 8 + 3]);
      unsigned b2 = cvtpk(v[ks * 8 + 6], v[ks * 8 + 7]);
      plswap(a1, b1);
      plswap(a2, b2);
      pk[ks][0] = a1; pk[ks][1] = a2; pk[ks][2] = b1; pk[ks][3] = b2;
    }
    {
      const char* vbase = (const char*)sVc;
      __builtin_amdgcn_s_setprio(1);
#pragma unroll
      for (int ks = 0; ks < 4; ++ks) {
        bf16x8 pa = *(const bf16x8*)&pk[ks][0];
#pragma unroll
        for (int dblk = 0; dblk < 4; ++dblk) {
          int d = dblk * 32 + l31;
          int slot = (((d >> 6) * 8 + (2 * ks + hi)) ^ (d & 15));
          bf16x8 vf = *(const bf16x8*)(vbase + (d & 63) * 256 + slot * 16);
          acc[dblk] = mfma32(pa, vf, acc[dblk]);
        }
      }
      __builtin_amdgcn_s_setprio(0);
    }
    asm volatile("s_waitcnt vmcnt(0)" ::: "memory");
    __syncthreads();
    bf16_t* t1 = sKc; sKc = sKn; sKn = t1;
    bf16_t* t2 = sVc; sVc = sVn; sVn = t2;
  }

  float inv = 1.f / lrun;
  bcast[w][l31] = inv;
  asm volatile("s_waitcnt lgkmcnt(0)" ::: "memory");
  __builtin_amdgcn_sched_barrier(0);
  bf16_t* ob = AO + ((size_t)b * Sc + q0) * Dc + h * HDc;
#pragma unroll
  for (int g4 = 0; g4 < 4; ++g4) {
    f32x4 ir = *(const f32x4*)(&bcast[w][8 * g4 + 4 * hi]);
#pragma unroll
    for (int j = 0; j < 4; ++j) {
      int q = 8 * g4 + 4 * hi + j;
#pragma unroll
      for (int dblk = 0; dblk < 4; ++dblk)
        ob[(size_t)q * Dc + dblk * 32 + l31] = (bf16_t)(acc[dblk][g4 * 4 + j] * ir[j]);
    }
  }
}

#define MB(x) ((size_t)(x) << 20)

extern "C" void kernel_launch(void* const* d_in, const int* in_sizes, int n_in,
                              void* d_out, int out_size, void* d_ws, size_t ws_size,
                              hipStream_t stream) {
  const float* x = (const float*)d_in[0];
  const int* mask = (const int*)d_in[1];
  const float* wq = (const float*)d_in[2];
  const float* bq = (const float*)d_in[3];
  const float* wk = (const float*)d_in[4];
  const float* bk = (const float*)d_in[5];
  const float* wv = (const float*)d_in[6];
  const float* bv = (const float*)d_in[7];
  const float* wo = (const float*)d_in[8];
  const float* bo = (const float*)d_in[9];
  float* out = (float*)d_out;

  char* ws = (char*)d_ws;
  bf16_t* xb     = (bf16_t*)(ws + MB(0));
  bf16_t* wqkvT  = (bf16_t*)(ws + MB(16));
  bf16_t* woT    = (bf16_t*)(ws + MB(40));
  bf16_t* qbuf   = (bf16_t*)(ws + MB(48));
  bf16_t* kbuf   = (bf16_t*)(ws + MB(64));
  bf16_t* vtb    = (bf16_t*)(ws + MB(80));
  bf16_t* ao     = (bf16_t*)(ws + MB(96));
  float2* rtbl   = (float2*)(ws + MB(112));

  cvt_bf16_kernel<<<8192, 256, 0, stream>>>(x, xb, (Mc * Dc) / 4);
  rope_table_kernel<<<Sc, 64, 0, stream>>>(rtbl);

  dim3 tg(64, 64, 4), tb(32, 8);
  transpose_cvt4_kernel<<<tg, tb, 0, stream>>>(wq, wk, wv, wo, wqkvT, woT);

  // fused QKV projection + RoPE: 16 M-tiles x 24 N-tiles = 384 blocks (256x256)
  gemmq_kernel<24><<<384, 512, 0, stream>>>(xb, wqkvT, bq, bk, bv, rtbl, qbuf, kbuf, vtb);

  attn_kernel<<<Bc * Hc * (Sc / 128), 256, 0, stream>>>(qbuf, kbuf, vtb, mask, ao);

  // output projection: 256x128 r6 structure, grid 256 (1 full round)
  gemmp_kernel<16><<<256, 512, 0, stream>>>(ao, woT, bo, out);
}

// Round 16
// 265.726 us; speedup vs baseline: 1.0537x; 1.0537x over previous
//
#include <hip/hip_runtime.h>

#define Bc 2
#define Sc 2048
#define Dc 2048
#define Hc 16
#define HDc 128
#define Mc 4096

typedef __bf16 bf16_t;
typedef __bf16 bf16x4 __attribute__((ext_vector_type(4)));
typedef __bf16 bf16x8 __attribute__((ext_vector_type(8)));
typedef float f32x4 __attribute__((ext_vector_type(4)));
typedef float f32x16 __attribute__((ext_vector_type(16)));

__device__ __forceinline__ f32x4 mfma16(bf16x8 a, bf16x8 b, f32x4 c) {
  return __builtin_amdgcn_mfma_f32_16x16x32_bf16(a, b, c, 0, 0, 0);
}
__device__ __forceinline__ f32x16 mfma32(bf16x8 a, bf16x8 b, f32x16 c) {
  return __builtin_amdgcn_mfma_f32_32x32x16_bf16(a, b, c, 0, 0, 0);
}

typedef const unsigned __attribute__((address_space(1))) gu32_t;
typedef unsigned __attribute__((address_space(3))) lu32_t;

__device__ __forceinline__ void gload_lds16(const void* g, void* l) {
  gu32_t* gp = (gu32_t*)(unsigned long long)g;
  lu32_t* lp = (lu32_t*)(unsigned)(unsigned long long)l;
  __builtin_amdgcn_global_load_lds(gp, lp, 16, 0, 0);
}

__device__ __forceinline__ unsigned cvtpk(float lo, float hi_) {
  unsigned r;
  asm("v_cvt_pk_bf16_f32 %0, %1, %2" : "=v"(r) : "v"(lo), "v"(hi_));
  return r;
}
__device__ __forceinline__ void plswap(unsigned& a, unsigned& b) {
  asm volatile("v_permlane32_swap_b32 %0, %1" : "+v"(a), "+v"(b));
}
// hardware 2^x (v_exp_f32 computes exp2 directly on gfx9xx)
__device__ __forceinline__ float fexp2(float x) {
  float r;
  asm("v_exp_f32 %0, %1" : "=v"(r) : "v"(x));
  return r;
}

// ---------------- convert x: fp32 -> bf16 ----------------
__global__ void cvt_bf16_kernel(const float* __restrict__ in, bf16_t* __restrict__ out, int n4) {
  int i = blockIdx.x * blockDim.x + threadIdx.x;
  if (i < n4) {
    float4 v = ((const float4*)in)[i];
    bf16x4 o;
    o[0] = (bf16_t)v.x; o[1] = (bf16_t)v.y; o[2] = (bf16_t)v.z; o[3] = (bf16_t)v.w;
    ((bf16x4*)out)[i] = o;
  }
}

// ---------------- rope cos/sin table: [2048][64] float2 ----------------
__global__ void rope_table_kernel(float2* __restrict__ tbl) {
  const int s = blockIdx.x, j = threadIdx.x;
  float freq = expf(-(float)j * (9.210340371976184f / 64.0f));
  float ang = (float)s * freq;
  float sn, cs;
  sincosf(ang, &sn, &cs);
  tbl[s * 64 + j] = make_float2(cs, sn);
}

// ---------------- transpose-convert 4 weights: (K,N) fp32 -> (N,K) bf16 ----------------
__global__ void transpose_cvt4_kernel(const float* __restrict__ w0, const float* __restrict__ w1,
                                      const float* __restrict__ w2, const float* __restrict__ w3,
                                      bf16_t* __restrict__ dqkv, bf16_t* __restrict__ dwo) {
  __shared__ float tile[32][33];
  const int z = blockIdx.z;
  const float* w = z == 0 ? w0 : (z == 1 ? w1 : (z == 2 ? w2 : w3));
  bf16_t* wt = z < 3 ? dqkv + (size_t)z * Dc * Dc : dwo;
  const int tx = threadIdx.x, ty = threadIdx.y;
  const int n0 = blockIdx.x * 32, k0 = blockIdx.y * 32;
#pragma unroll
  for (int i = 0; i < 32; i += 8)
    tile[ty + i][tx] = w[(size_t)(k0 + ty + i) * Dc + n0 + tx];
  __syncthreads();
#pragma unroll
  for (int i = 0; i < 32; i += 8)
    wt[(size_t)(n0 + ty + i) * Dc + k0 + tx] = (bf16_t)tile[tx][ty + i];
}

// ---------------- 256x128 GEMM, BK=64, ring-3 LDS, 2-phase, counted vmcnt(6) ----------------
// 8 waves = 4M x 2N, per-wave 64x64. Best-measured structure (r6/r11/r14).
// MODE 0: QKV-fused epilogue with fused interleaved RoPE on Q,K (NT8=48).
// MODE 2: fp32 out + bias (NT8=16).
template <int MODE, int NT8>
__global__ __launch_bounds__(512, 1) void gemmp_kernel(
    const bf16_t* __restrict__ A, const bf16_t* __restrict__ Bt,
    const float* __restrict__ bias0, const float* __restrict__ bias1,
    const float* __restrict__ bias2, const float2* __restrict__ tbl,
    void* __restrict__ out0, void* __restrict__ out1, void* __restrict__ out2) {
  __shared__ __align__(16) bf16_t sA[3][256 * 64];  // 96 KB
  __shared__ __align__(16) bf16_t sB[3][128 * 64];  // 48 KB
  const int tid = threadIdx.x;
  const int lane = tid & 63, wid = tid >> 6;
  const int l15 = lane & 15, g = lane >> 4;
  const int wrow = wid >> 1, wcol = wid & 1;

  const int nwg = 16 * NT8, cpx = nwg / 8;
  const int wgid = ((int)blockIdx.x & 7) * cpx + ((int)blockIdx.x >> 3);
  const int nt = wgid % NT8, mt = wgid / NT8;
  const int m0 = mt * 256, n0 = nt * 128;

  const bf16_t* Ab = A + (size_t)m0 * 2048;
  const bf16_t* Bb = Bt + (size_t)n0 * 2048;

#define GP_STAGE_A(kt, i_)                                           \
  {                                                                  \
    int s_ = (i_) * 512 + tid;                                       \
    int r_ = s_ >> 3;                                                \
    int c_ = ((s_ & 7) ^ (r_ & 7)) * 8;                              \
    gload_lds16(Ab + (size_t)r_ * 2048 + (kt) * 64 + c_,             \
                (char*)&sA[(kt) % 3][0] + s_ * 16);                  \
  }
#define GP_STAGE_B(kt, i_)                                           \
  {                                                                  \
    int s_ = (i_) * 512 + tid;                                       \
    int r_ = s_ >> 3;                                                \
    int c_ = ((s_ & 7) ^ (r_ & 7)) * 8;                              \
    gload_lds16(Bb + (size_t)r_ * 2048 + (kt) * 64 + c_,             \
                (char*)&sB[(kt) % 3][0] + s_ * 16);                  \
  }

  f32x4 acc[4][4] = {};

  GP_STAGE_A(0, 0) GP_STAGE_A(0, 1) GP_STAGE_A(0, 2) GP_STAGE_A(0, 3)
  GP_STAGE_B(0, 0) GP_STAGE_B(0, 1)
  GP_STAGE_A(1, 0) GP_STAGE_A(1, 1) GP_STAGE_A(1, 2) GP_STAGE_A(1, 3)
  GP_STAGE_B(1, 0) GP_STAGE_B(1, 1)

#define GP_BODY(t, DOSTG, VMSTR)                                               \
  {                                                                            \
    asm volatile("s_waitcnt vmcnt(" VMSTR ")" ::: "memory");                   \
    __builtin_amdgcn_s_barrier();                                              \
    __builtin_amdgcn_sched_barrier(0);                                         \
    const char* pA = (const char*)&sA[(t) % 3][0];                             \
    const char* pB = (const char*)&sB[(t) % 3][0];                             \
    bf16x8 af[4][2], bf0[2][2], bf1[2][2];                                     \
    _Pragma("unroll") for (int mi = 0; mi < 4; ++mi)                           \
        _Pragma("unroll") for (int ks = 0; ks < 2; ++ks) {                     \
      int r = wrow * 64 + mi * 16 + l15;                                       \
      af[mi][ks] = *(const bf16x8*)(pA + r * 128 + (((ks * 4 + g) ^ (r & 7)) * 16)); \
    }                                                                          \
    _Pragma("unroll") for (int ni = 0; ni < 2; ++ni)                           \
        _Pragma("unroll") for (int ks = 0; ks < 2; ++ks) {                     \
      int r = wcol * 64 + ni * 16 + l15;                                       \
      bf0[ni][ks] = *(const bf16x8*)(pB + r * 128 + (((ks * 4 + g) ^ (r & 7)) * 16)); \
    }                                                                          \
    if (DOSTG) { GP_STAGE_A((t) + 2, 0) GP_STAGE_A((t) + 2, 1) GP_STAGE_B((t) + 2, 0) } \
    __builtin_amdgcn_s_setprio(1);                                             \
    _Pragma("unroll") for (int mi = 0; mi < 4; ++mi)                           \
        _Pragma("unroll") for (int ni = 0; ni < 2; ++ni)                       \
            _Pragma("unroll") for (int ks = 0; ks < 2; ++ks)                   \
                acc[mi][ni] = mfma16(af[mi][ks], bf0[ni][ks], acc[mi][ni]);    \
    __builtin_amdgcn_s_setprio(0);                                             \
    __builtin_amdgcn_s_barrier();                                              \
    __builtin_amdgcn_sched_barrier(0);                                         \
    _Pragma("unroll") for (int ni = 0; ni < 2; ++ni)                           \
        _Pragma("unroll") for (int ks = 0; ks < 2; ++ks) {                     \
      int r = wcol * 64 + (ni + 2) * 16 + l15;                                 \
      bf1[ni][ks] = *(const bf16x8*)(pB + r * 128 + (((ks * 4 + g) ^ (r & 7)) * 16)); \
    }                                                                          \
    if (DOSTG) { GP_STAGE_A((t) + 2, 2) GP_STAGE_A((t) + 2, 3) GP_STAGE_B((t) + 2, 1) } \
    __builtin_amdgcn_s_setprio(1);                                             \
    _Pragma("unroll") for (int mi = 0; mi < 4; ++mi)                           \
        _Pragma("unroll") for (int ni = 0; ni < 2; ++ni)                       \
            _Pragma("unroll") for (int ks = 0; ks < 2; ++ks)                   \
                acc[mi][ni + 2] = mfma16(af[mi][ks], bf1[ni][ks], acc[mi][ni + 2]); \
    __builtin_amdgcn_s_setprio(0);                                             \
  }

  for (int t = 0; t < 30; ++t) GP_BODY(t, 1, "6");
  GP_BODY(30, 0, "6");
  GP_BODY(31, 0, "0");

#undef GP_BODY
#undef GP_STAGE_A
#undef GP_STAGE_B

  if (MODE == 2) {
#pragma unroll
    for (int mi = 0; mi < 4; ++mi) {
#pragma unroll
      for (int ni = 0; ni < 4; ++ni) {
        const int ncol = n0 + wcol * 64 + ni * 16 + l15;
        const float bv = bias0[ncol];
#pragma unroll
        for (int r = 0; r < 4; ++r) {
          const int mrow = m0 + wrow * 64 + mi * 16 + g * 4 + r;
          ((float*)out0)[(size_t)mrow * 2048 + ncol] = acc[mi][ni][r] + bv;
        }
      }
    }
  } else {
    const int proj = n0 >> 11;
    const float* bp = proj == 0 ? bias0 : (proj == 1 ? bias1 : bias2);
    bf16_t* op = (bf16_t*)(proj == 0 ? out0 : (proj == 1 ? out1 : out2));
#pragma unroll
    for (int mi = 0; mi < 4; ++mi) {
#pragma unroll
      for (int ni = 0; ni < 4; ++ni) {
        const int ncol = n0 + wcol * 64 + ni * 16 + l15;
        const int nloc = ncol & 2047;
        const float bv = bp[nloc];
        const int h = nloc >> 7, hd = nloc & 127;
        if (proj < 2) {
          const int j = hd >> 1;
#pragma unroll
          for (int r = 0; r < 4; ++r) {
            const int mrow = m0 + wrow * 64 + mi * 16 + g * 4 + r;
            const int b = mrow >> 11, sq = mrow & 2047;
            float vv = acc[mi][ni][r] + bv;
            float part = __shfl_xor(vv, 1);
            float2 cn = tbl[(size_t)sq * 64 + j];
            float ov = (l15 & 1) ? (part * cn.y + vv * cn.x)
                                 : (vv * cn.x - part * cn.y);
            op[(((size_t)(b * Hc + h) * Sc + sq) * HDc) + hd] = (bf16_t)ov;
          }
        } else {
#pragma unroll
          for (int r = 0; r < 4; ++r) {
            const int mrow = m0 + wrow * 64 + mi * 16 + g * 4 + r;
            const int b = mrow >> 11, sq = mrow & 2047;
            const float v = acc[mi][ni][r] + bv;
            op[(((size_t)(b * Hc + h) * HDc + hd) * Sc) + sq] = (bf16_t)v;
          }
        }
      }
    }
  }
}

// ---------------- flash attention, 32x32 swapped-QK^T, LDS dbuf K/V ----------------
// exp2-domain softmax: scale and mask bias pre-multiplied by log2(e).
__global__ __launch_bounds__(256, 2) void attn_kernel(
    const bf16_t* __restrict__ Q, const bf16_t* __restrict__ Kr,
    const bf16_t* __restrict__ Vt, const int* __restrict__ mask,
    bf16_t* __restrict__ AO) {
  __shared__ __align__(16) bf16_t sK[2][64 * 128];
  __shared__ __align__(16) bf16_t sV[2][64 * 128];
  __shared__ float mbias[Sc];
  __shared__ float bcast[4][32];
  const int tid = threadIdx.x;
  const int w = tid >> 6, lane = tid & 63;
  const int l31 = lane & 31, hi = lane >> 5;
  const int wbase = w * 64;

  const int bid = blockIdx.x;
  const int L = ((bid & 7) << 6) + (bid >> 3);
  const int qc = L & 15, h = (L >> 4) & 15, b = L >> 8;

  const int* mb = mask + b * Sc;
#pragma unroll
  for (int i = 0; i < Sc / 256; ++i)
    mbias[i * 256 + tid] = mb[i * 256 + tid] ? 0.f : -1.4426950408889634e9f;

  const int q0 = qc * 128 + w * 32;
  const bf16_t* qb = Q + ((size_t)(b * Hc + h) * Sc + q0) * HDc;
  const bf16_t* kb = Kr + ((size_t)(b * Hc + h) * Sc) * HDc;
  const bf16_t* vb = Vt + ((size_t)(b * Hc + h) * HDc) * Sc;

  bf16x8 qf[8];
  {
    const bf16_t* qr = qb + (size_t)l31 * HDc + hi * 8;
#pragma unroll
    for (int kk = 0; kk < 8; ++kk) qf[kk] = *(const bf16x8*)(qr + kk * 16);
  }

#define STAGE_KV(sKb, sVb, kv0_)                                             \
  {                                                                          \
    _Pragma("unroll") for (int p = 0; p < 4; ++p) {                          \
      int s_ = p * 256 + tid;                                                \
      int rk = s_ >> 4, ck = s_ & 15;                                        \
      gload_lds16(kb + (size_t)((kv0_) + rk) * HDc + ((ck ^ (rk & 15)) * 8), \
                  (char*)(sKb) + (size_t)(p * 256 + wbase) * 16);            \
      int d63 = s_ >> 4, sv = s_ & 15;                                       \
      int tmp = sv ^ (d63 & 15);                                             \
      int hb = tmp >> 3, cv = tmp & 7;                                       \
      gload_lds16(vb + (size_t)(hb * 64 + d63) * Sc + (kv0_) + cv * 8,       \
                  (char*)(sVb) + (size_t)(p * 256 + wbase) * 16);            \
    }                                                                        \
  }

  bf16_t* sKc = &sK[0][0];
  bf16_t* sKn = &sK[1][0];
  bf16_t* sVc = &sV[0][0];
  bf16_t* sVn = &sV[1][0];

  STAGE_KV(sKc, sVc, 0);
  asm volatile("s_waitcnt vmcnt(0)" ::: "memory");
  __syncthreads();

  f32x16 acc[4];
#pragma unroll
  for (int d = 0; d < 4; ++d) acc[d] = 0.f;
  float mrun = -3.0e38f, lrun = 0.f;
  const float scale2 = 0.12751744f;  // 128^-0.5 * log2(e)

  for (int kv0 = 0; kv0 < Sc; kv0 += 64) {
    if (kv0 + 64 < Sc) STAGE_KV(sKn, sVn, kv0 + 64);

    f32x16 s0 = 0.f, s1 = 0.f;
    {
      const char* kbase = (const char*)sKc;
      __builtin_amdgcn_s_setprio(1);
#pragma unroll
      for (int kk = 0; kk < 8; ++kk) {
        bf16x8 k0f = *(const bf16x8*)(kbase + l31 * 256 + (((2 * kk + hi) ^ (l31 & 15)) * 16));
        bf16x8 k1f = *(const bf16x8*)(kbase + (32 + l31) * 256 + (((2 * kk + hi) ^ ((32 + l31) & 15)) * 16));
        s0 = mfma32(k0f, qf[kk], s0);
        s1 = mfma32(k1f, qf[kk], s1);
      }
      __builtin_amdgcn_s_setprio(0);
    }
    float v[32];
    {
      const float* mp = mbias + kv0 + 4 * hi;
#pragma unroll
      for (int g4 = 0; g4 < 4; ++g4) {
        f32x4 b0 = *(const f32x4*)(mp + 8 * g4);
        f32x4 b1 = *(const f32x4*)(mp + 32 + 8 * g4);
#pragma unroll
        for (int j = 0; j < 4; ++j) {
          v[g4 * 4 + j] = s0[g4 * 4 + j] * scale2 + b0[j];
          v[16 + g4 * 4 + j] = s1[g4 * 4 + j] * scale2 + b1[j];
        }
      }
    }
    float t16[16];
#pragma unroll
    for (int r = 0; r < 16; ++r) t16[r] = fmaxf(v[r], v[r + 16]);
#pragma unroll
    for (int r = 0; r < 8; ++r) t16[r] = fmaxf(t16[r], t16[r + 8]);
#pragma unroll
    for (int r = 0; r < 4; ++r) t16[r] = fmaxf(t16[r], t16[r + 4]);
    float tm = fmaxf(fmaxf(t16[0], t16[1]), fmaxf(t16[2], t16[3]));
    tm = fmaxf(tm, __shfl_xor(tm, 32));
    if (__any(tm > mrun + 11.5415603f)) {
      float mnew = fmaxf(mrun, tm);
      float al = fexp2(mrun - mnew);
      mrun = mnew;
      lrun *= al;
      bcast[w][l31] = al;
      asm volatile("s_waitcnt lgkmcnt(0)" ::: "memory");
      __builtin_amdgcn_sched_barrier(0);
#pragma unroll
      for (int g4 = 0; g4 < 4; ++g4) {
        f32x4 alr = *(const f32x4*)(&bcast[w][8 * g4 + 4 * hi]);
#pragma unroll
        for (int dblk = 0; dblk < 4; ++dblk)
#pragma unroll
          for (int j = 0; j < 4; ++j) acc[dblk][g4 * 4 + j] *= alr[j];
      }
    }
    float ts = 0.f;
#pragma unroll
    for (int r = 0; r < 32; ++r) {
      v[r] = fexp2(v[r] - mrun);
      ts += v[r];
    }
    ts += __shfl_xor(ts, 32);
    lrun += ts;
    unsigned pk[4][4];
#pragma unroll
    for (int ks = 0; ks < 4; ++ks) {
      unsigned a1 = cvtpk(v[ks * 8 + 0], v[ks * 8 + 1]);
      unsigned b1 = cvtpk(v[ks * 8 + 4], v[ks * 8 + 5]);
      unsigned a2 = cvtpk(v[ks * 8 + 2], v[ks * 8 + 3]);
      unsigned b2 = cvtpk(v[ks * 8 + 6], v[ks * 8 + 7]);
      plswap(a1, b1);
      plswap(a2, b2);
      pk[ks][0] = a1; pk[ks][1] = a2; pk[ks][2] = b1; pk[ks][3] = b2;
    }
    {
      const char* vbase = (const char*)sVc;
      __builtin_amdgcn_s_setprio(1);
#pragma unroll
      for (int ks = 0; ks < 4; ++ks) {
        bf16x8 pa = *(const bf16x8*)&pk[ks][0];
#pragma unroll
        for (int dblk = 0; dblk < 4; ++dblk) {
          int d = dblk * 32 + l31;
          int slot = (((d >> 6) * 8 + (2 * ks + hi)) ^ (d & 15));
          bf16x8 vf = *(const bf16x8*)(vbase + (d & 63) * 256 + slot * 16);
          acc[dblk] = mfma32(pa, vf, acc[dblk]);
        }
      }
      __builtin_amdgcn_s_setprio(0);
    }
    asm volatile("s_waitcnt vmcnt(0)" ::: "memory");
    __syncthreads();
    bf16_t* t1 = sKc; sKc = sKn; sKn = t1;
    bf16_t* t2 = sVc; sVc = sVn; sVn = t2;
  }

  float inv = 1.f / lrun;
  bcast[w][l31] = inv;
  asm volatile("s_waitcnt lgkmcnt(0)" ::: "memory");
  __builtin_amdgcn_sched_barrier(0);
  bf16_t* ob = AO + ((size_t)b * Sc + q0) * Dc + h * HDc;
#pragma unroll
  for (int g4 = 0; g4 < 4; ++g4) {
    f32x4 ir = *(const f32x4*)(&bcast[w][8 * g4 + 4 * hi]);
#pragma unroll
    for (int j = 0; j < 4; ++j) {
      int q = 8 * g4 + 4 * hi + j;
#pragma unroll
      for (int dblk = 0; dblk < 4; ++dblk)
        ob[(size_t)q * Dc + dblk * 32 + l31] = (bf16_t)(acc[dblk][g4 * 4 + j] * ir[j]);
    }
  }
}

#define MB(x) ((size_t)(x) << 20)

extern "C" void kernel_launch(void* const* d_in, const int* in_sizes, int n_in,
                              void* d_out, int out_size, void* d_ws, size_t ws_size,
                              hipStream_t stream) {
  const float* x = (const float*)d_in[0];
  const int* mask = (const int*)d_in[1];
  const float* wq = (const float*)d_in[2];
  const float* bq = (const float*)d_in[3];
  const float* wk = (const float*)d_in[4];
  const float* bk = (const float*)d_in[5];
  const float* wv = (const float*)d_in[6];
  const float* bv = (const float*)d_in[7];
  const float* wo = (const float*)d_in[8];
  const float* bo = (const float*)d_in[9];
  float* out = (float*)d_out;

  char* ws = (char*)d_ws;
  bf16_t* xb     = (bf16_t*)(ws + MB(0));
  bf16_t* wqkvT  = (bf16_t*)(ws + MB(16));
  bf16_t* woT    = (bf16_t*)(ws + MB(40));
  bf16_t* qbuf   = (bf16_t*)(ws + MB(48));
  bf16_t* kbuf   = (bf16_t*)(ws + MB(64));
  bf16_t* vtb    = (bf16_t*)(ws + MB(80));
  bf16_t* ao     = (bf16_t*)(ws + MB(96));
  float2* rtbl   = (float2*)(ws + MB(112));

  cvt_bf16_kernel<<<8192, 256, 0, stream>>>(x, xb, (Mc * Dc) / 4);
  rope_table_kernel<<<Sc, 64, 0, stream>>>(rtbl);

  dim3 tg(64, 64, 4), tb(32, 8);
  transpose_cvt4_kernel<<<tg, tb, 0, stream>>>(wq, wk, wv, wo, wqkvT, woT);

  gemmp_kernel<0, 48><<<768, 512, 0, stream>>>(xb, wqkvT, bq, bk, bv, rtbl, qbuf, kbuf, vtb);

  attn_kernel<<<Bc * Hc * (Sc / 128), 256, 0, stream>>>(qbuf, kbuf, vtb, mask, ao);

  gemmp_kernel<2, 16><<<256, 512, 0, stream>>>(ao, woT, bo, bo, bo, rtbl, out, out, out);
}

// Round 17
// 262.880 us; speedup vs baseline: 1.0651x; 1.0108x over previous
//
#include <hip/hip_runtime.h>

#define Bc 2
#define Sc 2048
#define Dc 2048
#define Hc 16
#define HDc 128
#define Mc 4096

typedef __bf16 bf16_t;
typedef __bf16 bf16x4 __attribute__((ext_vector_type(4)));
typedef __bf16 bf16x8 __attribute__((ext_vector_type(8)));
typedef float f32x4 __attribute__((ext_vector_type(4)));
typedef float f32x16 __attribute__((ext_vector_type(16)));

__device__ __forceinline__ f32x4 mfma16(bf16x8 a, bf16x8 b, f32x4 c) {
  return __builtin_amdgcn_mfma_f32_16x16x32_bf16(a, b, c, 0, 0, 0);
}
__device__ __forceinline__ f32x16 mfma32(bf16x8 a, bf16x8 b, f32x16 c) {
  return __builtin_amdgcn_mfma_f32_32x32x16_bf16(a, b, c, 0, 0, 0);
}

typedef const unsigned __attribute__((address_space(1))) gu32_t;
typedef unsigned __attribute__((address_space(3))) lu32_t;

__device__ __forceinline__ void gload_lds16(const void* g, void* l) {
  gu32_t* gp = (gu32_t*)(unsigned long long)g;
  lu32_t* lp = (lu32_t*)(unsigned)(unsigned long long)l;
  __builtin_amdgcn_global_load_lds(gp, lp, 16, 0, 0);
}

__device__ __forceinline__ unsigned cvtpk(float lo, float hi_) {
  unsigned r;
  asm("v_cvt_pk_bf16_f32 %0, %1, %2" : "=v"(r) : "v"(lo), "v"(hi_));
  return r;
}
__device__ __forceinline__ void plswap(unsigned& a, unsigned& b) {
  asm volatile("v_permlane32_swap_b32 %0, %1" : "+v"(a), "+v"(b));
}
// hardware 2^x (v_exp_f32 computes exp2 directly on gfx9xx)
__device__ __forceinline__ float fexp2(float x) {
  float r;
  asm("v_exp_f32 %0, %1" : "=v"(r) : "v"(x));
  return r;
}

// ---------------- convert x: fp32 -> bf16 ----------------
__global__ void cvt_bf16_kernel(const float* __restrict__ in, bf16_t* __restrict__ out, int n4) {
  int i = blockIdx.x * blockDim.x + threadIdx.x;
  if (i < n4) {
    float4 v = ((const float4*)in)[i];
    bf16x4 o;
    o[0] = (bf16_t)v.x; o[1] = (bf16_t)v.y; o[2] = (bf16_t)v.z; o[3] = (bf16_t)v.w;
    ((bf16x4*)out)[i] = o;
  }
}

// ---------------- rope cos/sin table: [2048][64] float2 ----------------
__global__ void rope_table_kernel(float2* __restrict__ tbl) {
  const int s = blockIdx.x, j = threadIdx.x;
  float freq = expf(-(float)j * (9.210340371976184f / 64.0f));
  float ang = (float)s * freq;
  float sn, cs;
  sincosf(ang, &sn, &cs);
  tbl[s * 64 + j] = make_float2(cs, sn);
}

// ---------------- transpose-convert 4 weights: (K,N) fp32 -> (N,K) bf16 ----------------
__global__ void transpose_cvt4_kernel(const float* __restrict__ w0, const float* __restrict__ w1,
                                      const float* __restrict__ w2, const float* __restrict__ w3,
                                      bf16_t* __restrict__ dqkv, bf16_t* __restrict__ dwo) {
  __shared__ float tile[32][33];
  const int z = blockIdx.z;
  const float* w = z == 0 ? w0 : (z == 1 ? w1 : (z == 2 ? w2 : w3));
  bf16_t* wt = z < 3 ? dqkv + (size_t)z * Dc * Dc : dwo;
  const int tx = threadIdx.x, ty = threadIdx.y;
  const int n0 = blockIdx.x * 32, k0 = blockIdx.y * 32;
#pragma unroll
  for (int i = 0; i < 32; i += 8)
    tile[ty + i][tx] = w[(size_t)(k0 + ty + i) * Dc + n0 + tx];
  __syncthreads();
#pragma unroll
  for (int i = 0; i < 32; i += 8)
    wt[(size_t)(n0 + ty + i) * Dc + k0 + tx] = (bf16_t)tile[tx][ty + i];
}

// ---------------- 256x128 GEMM, BK=64, ring-3 LDS, 2-phase, counted vmcnt(6) ----------------
// 8 waves = 4M x 2N, per-wave 64x64. Best-measured structure (r6/r11/r14).
// 2-D rectangular XCD chunking: 32 co-resident blocks/XCD = 8mt x 4nt rect
// -> per-XCD L2 working set 10 MB (vs 17 MB 1-D order).
// MODE 0: QKV-fused epilogue with fused interleaved RoPE on Q,K (NT8=48).
// MODE 2: fp32 out + bias (NT8=16).
template <int MODE, int NT8>
__global__ __launch_bounds__(512, 1) void gemmp_kernel(
    const bf16_t* __restrict__ A, const bf16_t* __restrict__ Bt,
    const float* __restrict__ bias0, const float* __restrict__ bias1,
    const float* __restrict__ bias2, const float2* __restrict__ tbl,
    void* __restrict__ out0, void* __restrict__ out1, void* __restrict__ out2) {
  __shared__ __align__(16) bf16_t sA[3][256 * 64];  // 96 KB
  __shared__ __align__(16) bf16_t sB[3][128 * 64];  // 48 KB
  const int tid = threadIdx.x;
  const int lane = tid & 63, wid = tid >> 6;
  const int l15 = lane & 15, g = lane >> 4;
  const int wrow = wid >> 1, wcol = wid & 1;

  const int nwg = 16 * NT8, cpx = nwg / 8;
  const int wgid = ((int)blockIdx.x & 7) * cpx + ((int)blockIdx.x >> 3);
  // 2-D rect chunking: 32 consecutive wgids = 8mt x 4nt rectangle
  const int rect = wgid >> 5, local = wgid & 31;
  const int mt = (rect / (NT8 / 4)) * 8 + (local >> 2);
  const int nt = (rect % (NT8 / 4)) * 4 + (local & 3);
  const int m0 = mt * 256, n0 = nt * 128;

  const bf16_t* Ab = A + (size_t)m0 * 2048;
  const bf16_t* Bb = Bt + (size_t)n0 * 2048;

#define GP_STAGE_A(kt, i_)                                           \
  {                                                                  \
    int s_ = (i_) * 512 + tid;                                       \
    int r_ = s_ >> 3;                                                \
    int c_ = ((s_ & 7) ^ (r_ & 7)) * 8;                              \
    gload_lds16(Ab + (size_t)r_ * 2048 + (kt) * 64 + c_,             \
                (char*)&sA[(kt) % 3][0] + s_ * 16);                  \
  }
#define GP_STAGE_B(kt, i_)                                           \
  {                                                                  \
    int s_ = (i_) * 512 + tid;                                       \
    int r_ = s_ >> 3;                                                \
    int c_ = ((s_ & 7) ^ (r_ & 7)) * 8;                              \
    gload_lds16(Bb + (size_t)r_ * 2048 + (kt) * 64 + c_,             \
                (char*)&sB[(kt) % 3][0] + s_ * 16);                  \
  }

  f32x4 acc[4][4] = {};

  GP_STAGE_A(0, 0) GP_STAGE_A(0, 1) GP_STAGE_A(0, 2) GP_STAGE_A(0, 3)
  GP_STAGE_B(0, 0) GP_STAGE_B(0, 1)
  GP_STAGE_A(1, 0) GP_STAGE_A(1, 1) GP_STAGE_A(1, 2) GP_STAGE_A(1, 3)
  GP_STAGE_B(1, 0) GP_STAGE_B(1, 1)

#define GP_BODY(t, DOSTG, VMSTR)                                               \
  {                                                                            \
    asm volatile("s_waitcnt vmcnt(" VMSTR ")" ::: "memory");                   \
    __builtin_amdgcn_s_barrier();                                              \
    __builtin_amdgcn_sched_barrier(0);                                         \
    const char* pA = (const char*)&sA[(t) % 3][0];                             \
    const char* pB = (const char*)&sB[(t) % 3][0];                             \
    bf16x8 af[4][2], bf0[2][2], bf1[2][2];                                     \
    _Pragma("unroll") for (int mi = 0; mi < 4; ++mi)                           \
        _Pragma("unroll") for (int ks = 0; ks < 2; ++ks) {                     \
      int r = wrow * 64 + mi * 16 + l15;                                       \
      af[mi][ks] = *(const bf16x8*)(pA + r * 128 + (((ks * 4 + g) ^ (r & 7)) * 16)); \
    }                                                                          \
    _Pragma("unroll") for (int ni = 0; ni < 2; ++ni)                           \
        _Pragma("unroll") for (int ks = 0; ks < 2; ++ks) {                     \
      int r = wcol * 64 + ni * 16 + l15;                                       \
      bf0[ni][ks] = *(const bf16x8*)(pB + r * 128 + (((ks * 4 + g) ^ (r & 7)) * 16)); \
    }                                                                          \
    if (DOSTG) { GP_STAGE_A((t) + 2, 0) GP_STAGE_A((t) + 2, 1) GP_STAGE_B((t) + 2, 0) } \
    __builtin_amdgcn_s_setprio(1);                                             \
    _Pragma("unroll") for (int mi = 0; mi < 4; ++mi)                           \
        _Pragma("unroll") for (int ni = 0; ni < 2; ++ni)                       \
            _Pragma("unroll") for (int ks = 0; ks < 2; ++ks)                   \
                acc[mi][ni] = mfma16(af[mi][ks], bf0[ni][ks], acc[mi][ni]);    \
    __builtin_amdgcn_s_setprio(0);                                             \
    __builtin_amdgcn_s_barrier();                                              \
    __builtin_amdgcn_sched_barrier(0);                                         \
    _Pragma("unroll") for (int ni = 0; ni < 2; ++ni)                           \
        _Pragma("unroll") for (int ks = 0; ks < 2; ++ks) {                     \
      int r = wcol * 64 + (ni + 2) * 16 + l15;                                 \
      bf1[ni][ks] = *(const bf16x8*)(pB + r * 128 + (((ks * 4 + g) ^ (r & 7)) * 16)); \
    }                                                                          \
    if (DOSTG) { GP_STAGE_A((t) + 2, 2) GP_STAGE_A((t) + 2, 3) GP_STAGE_B((t) + 2, 1) } \
    __builtin_amdgcn_s_setprio(1);                                             \
    _Pragma("unroll") for (int mi = 0; mi < 4; ++mi)                           \
        _Pragma("unroll") for (int ni = 0; ni < 2; ++ni)                       \
            _Pragma("unroll") for (int ks = 0; ks < 2; ++ks)                   \
                acc[mi][ni + 2] = mfma16(af[mi][ks], bf1[ni][ks], acc[mi][ni + 2]); \
    __builtin_amdgcn_s_setprio(0);                                             \
  }

  for (int t = 0; t < 30; ++t) GP_BODY(t, 1, "6");
  GP_BODY(30, 0, "6");
  GP_BODY(31, 0, "0");

#undef GP_BODY
#undef GP_STAGE_A
#undef GP_STAGE_B

  if (MODE == 2) {
#pragma unroll
    for (int mi = 0; mi < 4; ++mi) {
#pragma unroll
      for (int ni = 0; ni < 4; ++ni) {
        const int ncol = n0 + wcol * 64 + ni * 16 + l15;
        const float bv = bias0[ncol];
#pragma unroll
        for (int r = 0; r < 4; ++r) {
          const int mrow = m0 + wrow * 64 + mi * 16 + g * 4 + r;
          ((float*)out0)[(size_t)mrow * 2048 + ncol] = acc[mi][ni][r] + bv;
        }
      }
    }
  } else {
    const int proj = n0 >> 11;
    const float* bp = proj == 0 ? bias0 : (proj == 1 ? bias1 : bias2);
    bf16_t* op = (bf16_t*)(proj == 0 ? out0 : (proj == 1 ? out1 : out2));
#pragma unroll
    for (int mi = 0; mi < 4; ++mi) {
#pragma unroll
      for (int ni = 0; ni < 4; ++ni) {
        const int ncol = n0 + wcol * 64 + ni * 16 + l15;
        const int nloc = ncol & 2047;
        const float bv = bp[nloc];
        const int h = nloc >> 7, hd = nloc & 127;
        if (proj < 2) {
          const int j = hd >> 1;
#pragma unroll
          for (int r = 0; r < 4; ++r) {
            const int mrow = m0 + wrow * 64 + mi * 16 + g * 4 + r;
            const int b = mrow >> 11, sq = mrow & 2047;
            float vv = acc[mi][ni][r] + bv;
            float part = __shfl_xor(vv, 1);
            float2 cn = tbl[(size_t)sq * 64 + j];
            float ov = (l15 & 1) ? (part * cn.y + vv * cn.x)
                                 : (vv * cn.x - part * cn.y);
            op[(((size_t)(b * Hc + h) * Sc + sq) * HDc) + hd] = (bf16_t)ov;
          }
        } else {
#pragma unroll
          for (int r = 0; r < 4; ++r) {
            const int mrow = m0 + wrow * 64 + mi * 16 + g * 4 + r;
            const int b = mrow >> 11, sq = mrow & 2047;
            const float v = acc[mi][ni][r] + bv;
            op[(((size_t)(b * Hc + h) * HDc + hd) * Sc) + sq] = (bf16_t)v;
          }
        }
      }
    }
  }
}

// ---------------- flash attention, 32x32 swapped-QK^T, LDS dbuf K/V ----------------
// exp2-domain softmax: scale and mask bias pre-multiplied by log2(e).
__global__ __launch_bounds__(256, 2) void attn_kernel(
    const bf16_t* __restrict__ Q, const bf16_t* __restrict__ Kr,
    const bf16_t* __restrict__ Vt, const int* __restrict__ mask,
    bf16_t* __restrict__ AO) {
  __shared__ __align__(16) bf16_t sK[2][64 * 128];
  __shared__ __align__(16) bf16_t sV[2][64 * 128];
  __shared__ float mbias[Sc];
  __shared__ float bcast[4][32];
  const int tid = threadIdx.x;
  const int w = tid >> 6, lane = tid & 63;
  const int l31 = lane & 31, hi = lane >> 5;
  const int wbase = w * 64;

  const int bid = blockIdx.x;
  const int L = ((bid & 7) << 6) + (bid >> 3);
  const int qc = L & 15, h = (L >> 4) & 15, b = L >> 8;

  const int* mb = mask + b * Sc;
#pragma unroll
  for (int i = 0; i < Sc / 256; ++i)
    mbias[i * 256 + tid] = mb[i * 256 + tid] ? 0.f : -1.4426950408889634e9f;

  const int q0 = qc * 128 + w * 32;
  const bf16_t* qb = Q + ((size_t)(b * Hc + h) * Sc + q0) * HDc;
  const bf16_t* kb = Kr + ((size_t)(b * Hc + h) * Sc) * HDc;
  const bf16_t* vb = Vt + ((size_t)(b * Hc + h) * HDc) * Sc;

  bf16x8 qf[8];
  {
    const bf16_t* qr = qb + (size_t)l31 * HDc + hi * 8;
#pragma unroll
    for (int kk = 0; kk < 8; ++kk) qf[kk] = *(const bf16x8*)(qr + kk * 16);
  }

#define STAGE_KV(sKb, sVb, kv0_)                                             \
  {                                                                          \
    _Pragma("unroll") for (int p = 0; p < 4; ++p) {                          \
      int s_ = p * 256 + tid;                                                \
      int rk = s_ >> 4, ck = s_ & 15;                                        \
      gload_lds16(kb + (size_t)((kv0_) + rk) * HDc + ((ck ^ (rk & 15)) * 8), \
                  (char*)(sKb) + (size_t)(p * 256 + wbase) * 16);            \
      int d63 = s_ >> 4, sv = s_ & 15;                                       \
      int tmp = sv ^ (d63 & 15);                                             \
      int hb = tmp >> 3, cv = tmp & 7;                                       \
      gload_lds16(vb + (size_t)(hb * 64 + d63) * Sc + (kv0_) + cv * 8,       \
                  (char*)(sVb) + (size_t)(p * 256 + wbase) * 16);            \
    }                                                                        \
  }

  bf16_t* sKc = &sK[0][0];
  bf16_t* sKn = &sK[1][0];
  bf16_t* sVc = &sV[0][0];
  bf16_t* sVn = &sV[1][0];

  STAGE_KV(sKc, sVc, 0);
  asm volatile("s_waitcnt vmcnt(0)" ::: "memory");
  __syncthreads();

  f32x16 acc[4];
#pragma unroll
  for (int d = 0; d < 4; ++d) acc[d] = 0.f;
  float mrun = -3.0e38f, lrun = 0.f;
  const float scale2 = 0.12751744f;  // 128^-0.5 * log2(e)

  for (int kv0 = 0; kv0 < Sc; kv0 += 64) {
    if (kv0 + 64 < Sc) STAGE_KV(sKn, sVn, kv0 + 64);

    f32x16 s0 = 0.f, s1 = 0.f;
    {
      const char* kbase = (const char*)sKc;
      __builtin_amdgcn_s_setprio(1);
#pragma unroll
      for (int kk = 0; kk < 8; ++kk) {
        bf16x8 k0f = *(const bf16x8*)(kbase + l31 * 256 + (((2 * kk + hi) ^ (l31 & 15)) * 16));
        bf16x8 k1f = *(const bf16x8*)(kbase + (32 + l31) * 256 + (((2 * kk + hi) ^ ((32 + l31) & 15)) * 16));
        s0 = mfma32(k0f, qf[kk], s0);
        s1 = mfma32(k1f, qf[kk], s1);
      }
      __builtin_amdgcn_s_setprio(0);
    }
    float v[32];
    {
      const float* mp = mbias + kv0 + 4 * hi;
#pragma unroll
      for (int g4 = 0; g4 < 4; ++g4) {
        f32x4 b0 = *(const f32x4*)(mp + 8 * g4);
        f32x4 b1 = *(const f32x4*)(mp + 32 + 8 * g4);
#pragma unroll
        for (int j = 0; j < 4; ++j) {
          v[g4 * 4 + j] = s0[g4 * 4 + j] * scale2 + b0[j];
          v[16 + g4 * 4 + j] = s1[g4 * 4 + j] * scale2 + b1[j];
        }
      }
    }
    float t16[16];
#pragma unroll
    for (int r = 0; r < 16; ++r) t16[r] = fmaxf(v[r], v[r + 16]);
#pragma unroll
    for (int r = 0; r < 8; ++r) t16[r] = fmaxf(t16[r], t16[r + 8]);
#pragma unroll
    for (int r = 0; r < 4; ++r) t16[r] = fmaxf(t16[r], t16[r + 4]);
    float tm = fmaxf(fmaxf(t16[0], t16[1]), fmaxf(t16[2], t16[3]));
    tm = fmaxf(tm, __shfl_xor(tm, 32));
    if (__any(tm > mrun + 11.5415603f)) {
      float mnew = fmaxf(mrun, tm);
      float al = fexp2(mrun - mnew);
      mrun = mnew;
      lrun *= al;
      bcast[w][l31] = al;
      asm volatile("s_waitcnt lgkmcnt(0)" ::: "memory");
      __builtin_amdgcn_sched_barrier(0);
#pragma unroll
      for (int g4 = 0; g4 < 4; ++g4) {
        f32x4 alr = *(const f32x4*)(&bcast[w][8 * g4 + 4 * hi]);
#pragma unroll
        for (int dblk = 0; dblk < 4; ++dblk)
#pragma unroll
          for (int j = 0; j < 4; ++j) acc[dblk][g4 * 4 + j] *= alr[j];
      }
    }
    float ts = 0.f;
#pragma unroll
    for (int r = 0; r < 32; ++r) {
      v[r] = fexp2(v[r] - mrun);
      ts += v[r];
    }
    ts += __shfl_xor(ts, 32);
    lrun += ts;
    unsigned pk[4][4];
#pragma unroll
    for (int ks = 0; ks < 4; ++ks) {
      unsigned a1 = cvtpk(v[ks * 8 + 0], v[ks * 8 + 1]);
      unsigned b1 = cvtpk(v[ks * 8 + 4], v[ks * 8 + 5]);
      unsigned a2 = cvtpk(v[ks * 8 + 2], v[ks * 8 + 3]);
      unsigned b2 = cvtpk(v[ks * 8 + 6], v[ks * 8 + 7]);
      plswap(a1, b1);
      plswap(a2, b2);
      pk[ks][0] = a1; pk[ks][1] = a2; pk[ks][2] = b1; pk[ks][3] = b2;
    }
    {
      const char* vbase = (const char*)sVc;
      __builtin_amdgcn_s_setprio(1);
#pragma unroll
      for (int ks = 0; ks < 4; ++ks) {
        bf16x8 pa = *(const bf16x8*)&pk[ks][0];
#pragma unroll
        for (int dblk = 0; dblk < 4; ++dblk) {
          int d = dblk * 32 + l31;
          int slot = (((d >> 6) * 8 + (2 * ks + hi)) ^ (d & 15));
          bf16x8 vf = *(const bf16x8*)(vbase + (d & 63) * 256 + slot * 16);
          acc[dblk] = mfma32(pa, vf, acc[dblk]);
        }
      }
      __builtin_amdgcn_s_setprio(0);
    }
    asm volatile("s_waitcnt vmcnt(0)" ::: "memory");
    __syncthreads();
    bf16_t* t1 = sKc; sKc = sKn; sKn = t1;
    bf16_t* t2 = sVc; sVc = sVn; sVn = t2;
  }

  float inv = 1.f / lrun;
  bcast[w][l31] = inv;
  asm volatile("s_waitcnt lgkmcnt(0)" ::: "memory");
  __builtin_amdgcn_sched_barrier(0);
  bf16_t* ob = AO + ((size_t)b * Sc + q0) * Dc + h * HDc;
#pragma unroll
  for (int g4 = 0; g4 < 4; ++g4) {
    f32x4 ir = *(const f32x4*)(&bcast[w][8 * g4 + 4 * hi]);
#pragma unroll
    for (int j = 0; j < 4; ++j) {
      int q = 8 * g4 + 4 * hi + j;
#pragma unroll
      for (int dblk = 0; dblk < 4; ++dblk)
        ob[(size_t)q * Dc + dblk * 32 + l31] = (bf16_t)(acc[dblk][g4 * 4 + j] * ir[j]);
    }
  }
}

#define MB(x) ((size_t)(x) << 20)

extern "C" void kernel_launch(void* const* d_in, const int* in_sizes, int n_in,
                              void* d_out, int out_size, void* d_ws, size_t ws_size,
                              hipStream_t stream) {
  const float* x = (const float*)d_in[0];
  const int* mask = (const int*)d_in[1];
  const float* wq = (const float*)d_in[2];
  const float* bq = (const float*)d_in[3];
  const float* wk = (const float*)d_in[4];
  const float* bk = (const float*)d_in[5];
  const float* wv = (const float*)d_in[6];
  const float* bv = (const float*)d_in[7];
  const float* wo = (const float*)d_in[8];
  const float* bo = (const float*)d_in[9];
  float* out = (float*)d_out;

  char* ws = (char*)d_ws;
  bf16_t* xb     = (bf16_t*)(ws + MB(0));
  bf16_t* wqkvT  = (bf16_t*)(ws + MB(16));
  bf16_t* woT    = (bf16_t*)(ws + MB(40));
  bf16_t* qbuf   = (bf16_t*)(ws + MB(48));
  bf16_t* kbuf   = (bf16_t*)(ws + MB(64));
  bf16_t* vtb    = (bf16_t*)(ws + MB(80));
  bf16_t* ao     = (bf16_t*)(ws + MB(96));
  float2* rtbl   = (float2*)(ws + MB(112));

  cvt_bf16_kernel<<<8192, 256, 0, stream>>>(x, xb, (Mc * Dc) / 4);
  rope_table_kernel<<<Sc, 64, 0, stream>>>(rtbl);

  dim3 tg(64, 64, 4), tb(32, 8);
  transpose_cvt4_kernel<<<tg, tb, 0, stream>>>(wq, wk, wv, wo, wqkvT, woT);

  gemmp_kernel<0, 48><<<768, 512, 0, stream>>>(xb, wqkvT, bq, bk, bv, rtbl, qbuf, kbuf, vtb);

  attn_kernel<<<Bc * Hc * (Sc / 128), 256, 0, stream>>>(qbuf, kbuf, vtb, mask, ao);

  gemmp_kernel<2, 16><<<256, 512, 0, stream>>>(ao, woT, bo, bo, bo, rtbl, out, out, out);
}